// Round 1
// baseline (183.011 us; speedup 1.0000x reference)
//
#include <hip/hip_runtime.h>

typedef unsigned short u16;
typedef __attribute__((ext_vector_type(8))) short bfrag;   // 8 bf16 = 4 VGPRs
typedef __attribute__((ext_vector_type(4))) float f32x4;

__device__ __forceinline__ u16 f2bf(float f) {
    unsigned u = __float_as_uint(f);
    u += 0x7FFFu + ((u >> 16) & 1u);           // RNE
    return (u16)(u >> 16);
}

__device__ __forceinline__ void glds16(const void* g, void* l) {
    __builtin_amdgcn_global_load_lds((__attribute__((address_space(1))) void*)g,
                                     (__attribute__((address_space(3))) void*)l,
                                     16, 0, 0);
}

// ---------------- convert: fp32 -> bf16 for x, Wq, Wk, Wv, Wo ----------------
__global__ __launch_bounds__(256) void convert_all(
    const float* __restrict__ x, const float* __restrict__ wq,
    const float* __restrict__ wk, const float* __restrict__ wv,
    const float* __restrict__ wo,
    u16* __restrict__ xb, u16* __restrict__ wqb, u16* __restrict__ wkb,
    u16* __restrict__ wvb, u16* __restrict__ wob) {
    const int XV = (2 * 2048 * 768) / 4;   // 786432 float4 jobs
    const int WV = (768 * 768) / 4;        // 147456 per weight
    int i = blockIdx.x * 256 + threadIdx.x;
    if (i >= XV + 4 * WV) return;
    const float4* src; u16* dst; int off;
    if (i < XV) { src = (const float4*)x; dst = xb; off = i; }
    else {
        int j = i - XV; int z = j / WV; off = j - z * WV;
        src = (const float4*)(z == 0 ? wq : z == 1 ? wk : z == 2 ? wv : wo);
        dst = (z == 0 ? wqb : z == 1 ? wkb : z == 2 ? wvb : wob);
    }
    float4 v = src[off];
    unsigned long long pk = (unsigned long long)f2bf(v.x)
        | ((unsigned long long)f2bf(v.y) << 16)
        | ((unsigned long long)f2bf(v.z) << 32)
        | ((unsigned long long)f2bf(v.w) << 48);
    *(unsigned long long*)(dst + off * 4) = pk;
}

// ---------------- GEMM core: Y = A @ W^T, A[M][768], W[N][768], bf16 ----------------
// 128x128 tile, BK=32, 4 waves (2x2), each wave 64x64 = 4x4 frags of 16x16x32.
// LDS [128][32] shorts; 16B units XOR-swizzled: stored u' = u ^ ((row>>1)&3)
// -> frag ds_read_b128 2-way conflict (free).
__device__ __forceinline__ void gemm_core(
    const u16* __restrict__ A, const u16* __restrict__ Bw, int m0,
    u16* a_lds, u16* b_lds, f32x4 acc[4][4]) {
    const int t = threadIdx.x;
    const int w = t >> 6, lane = t & 63, ln = lane & 15, lh = lane >> 4;
    const int wr = w >> 1, wc = w & 1;

    // staging: issue i covers units i*256+t; unit -> row=unit>>2, stored u'=unit&3,
    // actual u = u' ^ ((row>>1)&3). Global src pre-swizzled; LDS dest linear.
    const int row0 = t >> 2;
    const int u0 = (t & 3) ^ ((row0 >> 1) & 3);
    const int row1 = row0 + 64;
    const int u1 = (t & 3) ^ ((row1 >> 1) & 3);
    const u16* ga0 = A + (m0 + row0) * 768 + u0 * 8;
    const u16* ga1 = A + (m0 + row1) * 768 + u1 * 8;
    const u16* gb0 = Bw + row0 * 768 + u0 * 8;
    const u16* gb1 = Bw + row1 * 768 + u1 * 8;
    u16* la = a_lds + w * 64 * 8;   // wave-uniform LDS base, lane*16B added by HW
    u16* lb = b_lds + w * 64 * 8;

    for (int k0 = 0; k0 < 768; k0 += 32) {
        glds16(ga0 + k0, la);
        glds16(ga1 + k0, la + 256 * 8);
        glds16(gb0 + k0, lb);
        glds16(gb1 + k0, lb + 256 * 8);
        __syncthreads();
        bfrag aF[4], bF[4];
#pragma unroll
        for (int i = 0; i < 4; i++) {
            int ra = wr * 64 + i * 16 + ln;
            aF[i] = *(const bfrag*)(a_lds + ra * 32 + ((lh ^ ((ra >> 1) & 3)) * 8));
            int rb = wc * 64 + i * 16 + ln;
            bF[i] = *(const bfrag*)(b_lds + rb * 32 + ((lh ^ ((rb >> 1) & 3)) * 8));
        }
#pragma unroll
        for (int i = 0; i < 4; i++)
#pragma unroll
            for (int j = 0; j < 4; j++)
                acc[i][j] = __builtin_amdgcn_mfma_f32_16x16x32_bf16(
                    aF[i], bF[j], acc[i][j], 0, 0, 0);
        __syncthreads();
    }
}

// ---------------- QKV projection ----------------
__global__ __launch_bounds__(256) void gemm_qkv(
    const u16* __restrict__ xb,
    const u16* __restrict__ wqb, const u16* __restrict__ wkb, const u16* __restrict__ wvb,
    const float* __restrict__ bq, const float* __restrict__ bk, const float* __restrict__ bv,
    u16* __restrict__ q_ws, u16* __restrict__ k_ws, u16* __restrict__ v_ws) {
    __shared__ __align__(16) u16 a_lds[128 * 32];
    __shared__ __align__(16) u16 b_lds[128 * 32];
    const int m0 = blockIdx.x * 128;
    const int z = blockIdx.y / 6, nb = blockIdx.y % 6;
    const u16* Bw = (z == 0 ? wqb : z == 1 ? wkb : wvb) + nb * 128 * 768;
    const float* bias = (z == 0 ? bq : z == 1 ? bk : bv);
    u16* dst = (z == 0 ? q_ws : z == 1 ? k_ws : v_ws);

    f32x4 acc[4][4] = {};
    gemm_core(xb, Bw, m0, a_lds, b_lds, acc);

    const int t = threadIdx.x, w = t >> 6, lane = t & 63, ln = lane & 15, lh = lane >> 4;
    const int wr = w >> 1, wc = w & 1;
#pragma unroll
    for (int j = 0; j < 4; j++) {
        int nl = nb * 128 + wc * 64 + j * 16 + ln;   // 0..767
        int h = nl >> 6, d = nl & 63;
        float bb = bias[nl];
#pragma unroll
        for (int i = 0; i < 4; i++)
#pragma unroll
            for (int r = 0; r < 4; r++) {
                int m = m0 + wr * 64 + i * 16 + lh * 4 + r;   // b*2048 + s
                int b = m >> 11, s = m & 2047;
                dst[((b * 12 + h) * 2048 + s) * 64 + d] = f2bf(acc[i][j][r] + bb);
            }
    }
}

// ---------------- output projection ----------------
__global__ __launch_bounds__(256) void gemm_out(
    const u16* __restrict__ ob, const u16* __restrict__ wob,
    const float* __restrict__ bo, float* __restrict__ out) {
    __shared__ __align__(16) u16 a_lds[128 * 32];
    __shared__ __align__(16) u16 b_lds[128 * 32];
    const int m0 = blockIdx.x * 128, n0 = blockIdx.y * 128;
    f32x4 acc[4][4] = {};
    gemm_core(ob, wob + n0 * 768, m0, a_lds, b_lds, acc);
    const int t = threadIdx.x, w = t >> 6, lane = t & 63, ln = lane & 15, lh = lane >> 4;
    const int wr = w >> 1, wc = w & 1;
#pragma unroll
    for (int j = 0; j < 4; j++) {
        int n = n0 + wc * 64 + j * 16 + ln;
        float bb = bo[n];
#pragma unroll
        for (int i = 0; i < 4; i++)
#pragma unroll
            for (int r = 0; r < 4; r++) {
                int m = m0 + wr * 64 + i * 16 + lh * 4 + r;
                out[m * 768 + n] = acc[i][j][r] + bb;
            }
    }
}

// ---------------- attention ----------------
// grid (32 q-tiles, 24 bh). 4 waves x 16 q-rows (q-tile 64). K-chunks of 32.
// mask: allowed iff (k%256) <= (q%256). Chunk skip: block if k0%256 > qmod_max(block),
// wave if k0%256 > qmod_max(wave).
__global__ __launch_bounds__(256) void attn(
    const u16* __restrict__ q_ws, const u16* __restrict__ k_ws,
    const u16* __restrict__ v_ws, u16* __restrict__ o_ws) {
    __shared__ __align__(16) u16 k_lds[32 * 64];      // [k][d], units swizzled u^=(row&7)
    __shared__ __align__(16) u16 vt_lds[64 * 40];     // [d][k], pad 40 -> 80B rows
    __shared__ __align__(16) u16 p_lds[4][16 * 40];   // per-wave [q][k], pad 40

    const int t = threadIdx.x, w = t >> 6, lane = t & 63, ln = lane & 15, lh = lane >> 4;
    const int qt = blockIdx.x, bh = blockIdx.y;
    const int b = bh / 12, h = bh % 12;
    const int q0 = qt * 64, q0w = q0 + w * 16;
    const int qm0w = q0w & 255;
    const int qmaxb = (q0 & 255) + 63;

    const u16* Qb = q_ws + bh * 2048 * 64;
    const u16* Kb = k_ws + bh * 2048 * 64;
    const u16* Vb = v_ws + bh * 2048 * 64;

    // Q A-frags (held in regs): A[q=ln][d=(j*32)+lh*8+0..7]
    bfrag qA[2];
#pragma unroll
    for (int j = 0; j < 2; j++)
        qA[j] = *(const bfrag*)(Qb + (q0w + ln) * 64 + j * 32 + lh * 8);

    f32x4 O[4] = {};
    float mrow[4] = {-1e30f, -1e30f, -1e30f, -1e30f};
    float lrow[4] = {0.f, 0.f, 0.f, 0.f};

    const int krow = t >> 3, ku = (t & 7) ^ (krow & 7);   // K staging map
    u16* klb = k_lds + w * 64 * 8;                        // wave-uniform base
    const int vk = t & 31, vd0 = (t >> 5) << 3;           // V transpose staging map

    for (int k0 = 0; k0 < 2048; k0 += 32) {
        const int km0 = k0 & 255;
        if (km0 > qmaxb) continue;                        // uniform block skip
        // stage K (swizzled global src -> linear LDS)
        glds16(Kb + (k0 + krow) * 64 + ku * 8, klb);
        // stage V transposed via regs
        bfrag vv = *(const bfrag*)(Vb + (k0 + vk) * 64 + vd0);
#pragma unroll
        for (int j = 0; j < 8; j++)
            vt_lds[(vd0 + j) * 40 + vk] = (u16)vv[j];
        __syncthreads();

        if (km0 <= qm0w + 15) {                           // uniform wave skip
            bfrag kB[2][2];
#pragma unroll
            for (int kc = 0; kc < 2; kc++)
#pragma unroll
                for (int j = 0; j < 2; j++) {
                    int kr = kc * 16 + ln;
                    int up = (j * 4 + lh) ^ (kr & 7);
                    kB[kc][j] = *(const bfrag*)(k_lds + kr * 64 + up * 8);
                }
            f32x4 sF[2];
#pragma unroll
            for (int kc = 0; kc < 2; kc++) {
                f32x4 zz = {0.f, 0.f, 0.f, 0.f};
                zz = __builtin_amdgcn_mfma_f32_16x16x32_bf16(qA[0], kB[kc][0], zz, 0, 0, 0);
                sF[kc] = __builtin_amdgcn_mfma_f32_16x16x32_bf16(qA[1], kB[kc][1], zz, 0, 0, 0);
            }
            float fac[4];
#pragma unroll
            for (int r = 0; r < 4; r++) {
                int qm = qm0w + lh * 4 + r;
                bool ok0 = (km0 + ln) <= qm;
                bool ok1 = (km0 + 16 + ln) <= qm;
                float s0 = ok0 ? sF[0][r] * 0.125f : -1e30f;
                float s1 = ok1 ? sF[1][r] * 0.125f : -1e30f;
                float mx = fmaxf(s0, s1);
                mx = fmaxf(mx, __shfl_xor(mx, 1));
                mx = fmaxf(mx, __shfl_xor(mx, 2));
                mx = fmaxf(mx, __shfl_xor(mx, 4));
                mx = fmaxf(mx, __shfl_xor(mx, 8));
                float nm = fmaxf(mrow[r], mx);
                float f = __expf(mrow[r] - nm);
                float p0 = ok0 ? __expf(s0 - nm) : 0.f;   // predicated: avoids exp(0)=1 trap
                float p1 = ok1 ? __expf(s1 - nm) : 0.f;
                float ps = p0 + p1;
                ps += __shfl_xor(ps, 1);
                ps += __shfl_xor(ps, 2);
                ps += __shfl_xor(ps, 4);
                ps += __shfl_xor(ps, 8);
                lrow[r] = lrow[r] * f + ps;
                mrow[r] = nm;
                fac[r] = f;
                p_lds[w][(lh * 4 + r) * 40 + ln] = f2bf(p0);
                p_lds[w][(lh * 4 + r) * 40 + 16 + ln] = f2bf(p1);
            }
#pragma unroll
            for (int dc = 0; dc < 4; dc++)
#pragma unroll
                for (int r = 0; r < 4; r++) O[dc][r] *= fac[r];
            // P A-frag: A[q=ln][k=lh*8+0..7] (same-wave LDS RAW, compiler waits)
            bfrag pA = *(const bfrag*)(&p_lds[w][ln * 40 + lh * 8]);
#pragma unroll
            for (int dc = 0; dc < 4; dc++) {
                bfrag vB = *(const bfrag*)(vt_lds + (dc * 16 + ln) * 40 + lh * 8);
                O[dc] = __builtin_amdgcn_mfma_f32_16x16x32_bf16(pA, vB, O[dc], 0, 0, 0);
            }
        }
        __syncthreads();
    }

    float inv[4];
#pragma unroll
    for (int r = 0; r < 4; r++) inv[r] = 1.0f / lrow[r];
#pragma unroll
    for (int dc = 0; dc < 4; dc++)
#pragma unroll
        for (int r = 0; r < 4; r++) {
            int q = q0w + lh * 4 + r;
            int d = dc * 16 + ln;
            o_ws[(b * 2048 + q) * 768 + h * 64 + d] = f2bf(O[dc][r] * inv[r]);
        }
}

// ---------------- launcher ----------------
extern "C" void kernel_launch(void* const* d_in, const int* in_sizes, int n_in,
                              void* d_out, int out_size, void* d_ws, size_t ws_size,
                              hipStream_t stream) {
    const float* x  = (const float*)d_in[0];
    const float* Wq = (const float*)d_in[1];
    const float* bq = (const float*)d_in[2];
    const float* Wk = (const float*)d_in[3];
    const float* bk = (const float*)d_in[4];
    const float* Wv = (const float*)d_in[5];
    const float* bv = (const float*)d_in[6];
    const float* Wo = (const float*)d_in[7];
    const float* bo = (const float*)d_in[8];
    float* out = (float*)d_out;

    char* p = (char*)d_ws;
    u16* xb  = (u16*)p; p += (size_t)2 * 2048 * 768 * 2;   // 6.3 MB
    u16* wqb = (u16*)p; p += (size_t)768 * 768 * 2;
    u16* wkb = (u16*)p; p += (size_t)768 * 768 * 2;
    u16* wvb = (u16*)p; p += (size_t)768 * 768 * 2;
    u16* wob = (u16*)p; p += (size_t)768 * 768 * 2;
    u16* q_ws = (u16*)p; p += (size_t)24 * 2048 * 64 * 2;  // [bh][s][64]
    u16* k_ws = (u16*)p; p += (size_t)24 * 2048 * 64 * 2;
    u16* v_ws = (u16*)p; p += (size_t)24 * 2048 * 64 * 2;
    u16* o_ws = (u16*)p; p += (size_t)4096 * 768 * 2;      // [b*s][h*d]

    convert_all<<<5376, 256, 0, stream>>>(x, Wq, Wk, Wv, Wo, xb, wqb, wkb, wvb, wob);
    gemm_qkv<<<dim3(32, 18), 256, 0, stream>>>(xb, wqb, wkb, wvb, bq, bk, bv, q_ws, k_ws, v_ws);
    attn<<<dim3(32, 24), 256, 0, stream>>>(q_ws, k_ws, v_ws, o_ws);
    gemm_out<<<dim3(32, 6), 256, 0, stream>>>(o_ws, wob, bo, out);
}

// Round 2
// 118.880 us; speedup vs baseline: 1.5395x; 1.5395x over previous
//
#include <hip/hip_runtime.h>

typedef unsigned short u16;
typedef unsigned int u32;
typedef __attribute__((ext_vector_type(8))) short bfrag;    // 8 bf16 = 4 VGPRs
typedef __attribute__((ext_vector_type(4))) float f32x4;
typedef __attribute__((ext_vector_type(16))) float f32x16;
typedef __attribute__((ext_vector_type(4))) u32 u32x4;

#define QSCALE 0.18033688f   // 0.125 * log2(e): scores land in log2 domain

__device__ __forceinline__ u16 f2bf(float f) {
    unsigned u = __float_as_uint(f);
    u += 0x7FFFu + ((u >> 16) & 1u);           // RNE
    return (u16)(u >> 16);
}

__device__ __forceinline__ u32 cvt_pk_bf16(float lo, float hi) {
    u32 r;
    asm("v_cvt_pk_bf16_f32 %0, %1, %2" : "=v"(r) : "v"(lo), "v"(hi));
    return r;
}

__device__ __forceinline__ void glds16(const void* g, void* l) {
    __builtin_amdgcn_global_load_lds((__attribute__((address_space(1))) void*)g,
                                     (__attribute__((address_space(3))) void*)l,
                                     16, 0, 0);
}

__device__ __forceinline__ f32x16 mfma32(bfrag a, bfrag b, f32x16 c) {
    return __builtin_amdgcn_mfma_f32_32x32x16_bf16(a, b, c, 0, 0, 0);
}

// ---------------- convert: fp32 -> bf16 for x, Wq, Wk, Wv, Wo ----------------
__global__ __launch_bounds__(256) void convert_all(
    const float* __restrict__ x, const float* __restrict__ wq,
    const float* __restrict__ wk, const float* __restrict__ wv,
    const float* __restrict__ wo,
    u16* __restrict__ xb, u16* __restrict__ wqb, u16* __restrict__ wkb,
    u16* __restrict__ wvb, u16* __restrict__ wob) {
    const int XV = (2 * 2048 * 768) / 4;
    const int WV = (768 * 768) / 4;
    int i = blockIdx.x * 256 + threadIdx.x;
    if (i >= XV + 4 * WV) return;
    const float4* src; u16* dst; int off;
    if (i < XV) { src = (const float4*)x; dst = xb; off = i; }
    else {
        int j = i - XV; int z = j / WV; off = j - z * WV;
        src = (const float4*)(z == 0 ? wq : z == 1 ? wk : z == 2 ? wv : wo);
        dst = (z == 0 ? wqb : z == 1 ? wkb : z == 2 ? wvb : wob);
    }
    float4 v = src[off];
    unsigned long long pk = (unsigned long long)f2bf(v.x)
        | ((unsigned long long)f2bf(v.y) << 16)
        | ((unsigned long long)f2bf(v.z) << 32)
        | ((unsigned long long)f2bf(v.w) << 48);
    *(unsigned long long*)(dst + off * 4) = pk;
}

// ---------------- GEMM core: Y = A @ W^T, A[M][768], W[N][768], bf16 ----------------
__device__ __forceinline__ void gemm_core(
    const u16* __restrict__ A, const u16* __restrict__ Bw, int m0,
    u16* a_lds, u16* b_lds, f32x4 acc[4][4]) {
    const int t = threadIdx.x;
    const int w = t >> 6, lane = t & 63, ln = lane & 15, lh = lane >> 4;
    const int wr = w >> 1, wc = w & 1;

    const int row0 = t >> 2;
    const int u0 = (t & 3) ^ ((row0 >> 1) & 3);
    const int row1 = row0 + 64;
    const int u1 = (t & 3) ^ ((row1 >> 1) & 3);
    const u16* ga0 = A + (m0 + row0) * 768 + u0 * 8;
    const u16* ga1 = A + (m0 + row1) * 768 + u1 * 8;
    const u16* gb0 = Bw + row0 * 768 + u0 * 8;
    const u16* gb1 = Bw + row1 * 768 + u1 * 8;
    u16* la = a_lds + w * 64 * 8;
    u16* lb = b_lds + w * 64 * 8;

    for (int k0 = 0; k0 < 768; k0 += 32) {
        glds16(ga0 + k0, la);
        glds16(ga1 + k0, la + 256 * 8);
        glds16(gb0 + k0, lb);
        glds16(gb1 + k0, lb + 256 * 8);
        __syncthreads();
        bfrag aF[4], bF[4];
#pragma unroll
        for (int i = 0; i < 4; i++) {
            int ra = wr * 64 + i * 16 + ln;
            aF[i] = *(const bfrag*)(a_lds + ra * 32 + ((lh ^ ((ra >> 1) & 3)) * 8));
            int rb = wc * 64 + i * 16 + ln;
            bF[i] = *(const bfrag*)(b_lds + rb * 32 + ((lh ^ ((rb >> 1) & 3)) * 8));
        }
#pragma unroll
        for (int i = 0; i < 4; i++)
#pragma unroll
            for (int j = 0; j < 4; j++)
                acc[i][j] = __builtin_amdgcn_mfma_f32_16x16x32_bf16(
                    aF[i], bF[j], acc[i][j], 0, 0, 0);
        __syncthreads();
    }
}

// ---------------- QKV projection ----------------
// Q: scaled by QSCALE, layout [bh][s][64].  K: [bh][s][64].  V: TRANSPOSED [bh][d][s].
__global__ __launch_bounds__(256) void gemm_qkv(
    const u16* __restrict__ xb,
    const u16* __restrict__ wqb, const u16* __restrict__ wkb, const u16* __restrict__ wvb,
    const float* __restrict__ bq, const float* __restrict__ bk, const float* __restrict__ bv,
    u16* __restrict__ q_ws, u16* __restrict__ k_ws, u16* __restrict__ vt_ws) {
    __shared__ __align__(16) u16 a_lds[128 * 32];
    __shared__ __align__(16) u16 b_lds[128 * 32];
    const int m0 = blockIdx.x * 128;
    const int z = blockIdx.y / 6, nb = blockIdx.y % 6;
    const u16* Bw = (z == 0 ? wqb : z == 1 ? wkb : wvb) + nb * 128 * 768;
    const float* bias = (z == 0 ? bq : z == 1 ? bk : bv);

    f32x4 acc[4][4] = {};
    gemm_core(xb, Bw, m0, a_lds, b_lds, acc);

    const int t = threadIdx.x, w = t >> 6, lane = t & 63, ln = lane & 15, lh = lane >> 4;
    const int wr = w >> 1, wc = w & 1;
    if (z == 2) {
        // V transposed store: pack 4 consecutive s as one 8B store
#pragma unroll
        for (int j = 0; j < 4; j++) {
            int nl = nb * 128 + wc * 64 + j * 16 + ln;
            int h = nl >> 6, d = nl & 63;
            float bb = bias[nl];
#pragma unroll
            for (int i = 0; i < 4; i++) {
                int mb = m0 + wr * 64 + i * 16 + lh * 4;
                int b = mb >> 11, s = mb & 2047;
                unsigned long long pk =
                      (unsigned long long)f2bf(acc[i][j][0] + bb)
                    | ((unsigned long long)f2bf(acc[i][j][1] + bb) << 16)
                    | ((unsigned long long)f2bf(acc[i][j][2] + bb) << 32)
                    | ((unsigned long long)f2bf(acc[i][j][3] + bb) << 48);
                *(unsigned long long*)(vt_ws + ((size_t)((b * 12 + h) * 64 + d)) * 2048 + s) = pk;
            }
        }
    } else {
        u16* dst = (z == 0 ? q_ws : k_ws);
        const float sc = (z == 0) ? QSCALE : 1.0f;
#pragma unroll
        for (int j = 0; j < 4; j++) {
            int nl = nb * 128 + wc * 64 + j * 16 + ln;
            int h = nl >> 6, d = nl & 63;
            float bb = bias[nl];
#pragma unroll
            for (int i = 0; i < 4; i++)
#pragma unroll
                for (int r = 0; r < 4; r++) {
                    int m = m0 + wr * 64 + i * 16 + lh * 4 + r;
                    int b = m >> 11, s = m & 2047;
                    dst[((size_t)((b * 12 + h) * 2048 + s)) * 64 + d] = f2bf((acc[i][j][r] + bb) * sc);
                }
        }
    }
}

// ---------------- output projection ----------------
__global__ __launch_bounds__(256) void gemm_out(
    const u16* __restrict__ ob, const u16* __restrict__ wob,
    const float* __restrict__ bo, float* __restrict__ out) {
    __shared__ __align__(16) u16 a_lds[128 * 32];
    __shared__ __align__(16) u16 b_lds[128 * 32];
    const int m0 = blockIdx.x * 128, n0 = blockIdx.y * 128;
    f32x4 acc[4][4] = {};
    gemm_core(ob, wob + n0 * 768, m0, a_lds, b_lds, acc);
    const int t = threadIdx.x, w = t >> 6, lane = t & 63, ln = lane & 15, lh = lane >> 4;
    const int wr = w >> 1, wc = w & 1;
#pragma unroll
    for (int j = 0; j < 4; j++) {
        int n = n0 + wc * 64 + j * 16 + ln;
        float bb = bo[n];
#pragma unroll
        for (int i = 0; i < 4; i++)
#pragma unroll
            for (int r = 0; r < 4; r++) {
                int m = m0 + wr * 64 + i * 16 + lh * 4 + r;
                out[m * 768 + n] = acc[i][j][r] + bb;
            }
    }
}

// ---------------- attention v2: swapped-QK^T 32x32, in-register softmax ----------------
// Block = 4 waves, all with SAME t7 = tile&7 (same mask budget) -> uniform chunk set.
// Wave w handles q-tile = t7 + 8*(half*4+w) (32 q rows). K/V 64-key chunks staged in
// swizzled LDS once per block. Scores in log2 domain (QSCALE folded into Q).
__global__ __launch_bounds__(256, 2) void attn2(
    const u16* __restrict__ q_ws, const u16* __restrict__ k_ws,
    const u16* __restrict__ vt_ws, u16* __restrict__ o_ws) {
    __shared__ __align__(16) u16 k_lds[64 * 64];   // [key][d], 16B units u^=key&7
    __shared__ __align__(16) u16 v_lds[64 * 64];   // [d][key], 16B units u^=d&7

    const int t = threadIdx.x, w = t >> 6, l = t & 63, lq = l & 31, H = l >> 5;
    // block decode: id%8 pins bh%8 to an XCD; heavy t7 dispatched first
    int id = blockIdx.x;
    int bh8 = id & 7, r = id >> 3;
    int bhq = r % 3, ch = r / 3;
    int t7 = 7 - (ch >> 1), half = ch & 1;
    int bh = bhq * 8 + bh8;
    int tile = t7 + 8 * (half * 4 + w);
    int qw0 = tile * 32, qm = t7 * 32;
    int b = bh / 12, h = bh % 12;

    const u16* Qb = q_ws + (size_t)bh * 2048 * 64;
    const u16* Kb = k_ws + (size_t)bh * 2048 * 64;
    const u16* Vt = vt_ws + (size_t)bh * 64 * 2048;

    bfrag qF[4];
#pragma unroll
    for (int kd = 0; kd < 4; kd++)
        qF[kd] = *(const bfrag*)(Qb + (size_t)(qw0 + lq) * 64 + kd * 16 + H * 8);

    f32x16 O0 = {}, O1 = {};
    float m = -1e30f, lsum = 0.f;

    const int npair = (t7 + 2) >> 1;
    // staging maps (linear LDS dest; global src pre-swizzled)
    const int skey = t >> 3;
    const int su = (t & 7) ^ (skey & 7);
    u16* kl0 = k_lds + (t >> 6) * 512;           // wave-uniform bases
    u16* kl1 = k_lds + 2048 + (t >> 6) * 512;
    u16* vl0 = v_lds + (t >> 6) * 512;
    u16* vl1 = v_lds + 2048 + (t >> 6) * 512;

    for (int win = 0; win < 8; ++win) {
        for (int pr = 0; pr < npair; ++pr) {
            const int cb = pr * 2;
            const int k0 = win * 256 + cb * 32;
            const bool c1 = (cb + 1) <= t7;
            // stage K [64 keys][64 d] and V [64 d][64 keys span k0..k0+63]
            glds16(Kb + (size_t)(k0 + skey) * 64 + su * 8, kl0);
            glds16(Kb + (size_t)(k0 + skey + 32) * 64 + su * 8, kl1);
            glds16(Vt + (size_t)skey * 2048 + k0 + su * 8, vl0);
            glds16(Vt + (size_t)(skey + 32) * 2048 + k0 + su * 8, vl1);
            __syncthreads();

            // S^T = K . Q  (32x32 per block; col = own query)
            f32x16 s0 = {}, s1 = {};
#pragma unroll
            for (int kd = 0; kd < 4; kd++) {
                int u = (kd * 2 + H) ^ (lq & 7);
                bfrag kf = *(const bfrag*)(k_lds + lq * 64 + u * 8);
                s0 = mfma32(kf, qF[kd], s0);
            }
            if (c1) {
#pragma unroll
                for (int kd = 0; kd < 4; kd++) {
                    int key = 32 + lq;
                    int u = (kd * 2 + H) ^ (key & 7);
                    bfrag kf = *(const bfrag*)(k_lds + key * 64 + u * 8);
                    s1 = mfma32(kf, qF[kd], s1);
                }
            }
            // V B-frags
            bfrag vB0[4], vB1[4];
#pragma unroll
            for (int kc = 0; kc < 4; kc++) {
                int u0 = (kc * 2 + H) ^ (lq & 7);
                vB0[kc] = *(const bfrag*)(v_lds + lq * 64 + u0 * 8);
                int d1 = 32 + lq;
                int u1 = (kc * 2 + H) ^ (d1 & 7);
                vB1[kc] = *(const bfrag*)(v_lds + d1 * 64 + u1 * 8);
            }

            // mask + in-lane max (rows = keys; allowed iff row <= dlt)
            const int dlt = qm - cb * 32 + lq;
            float pmax = -1e30f;
#pragma unroll
            for (int r2 = 0; r2 < 16; r2++) {
                int row = (r2 & 3) + 8 * (r2 >> 2) + 4 * H;
                if (row > dlt) s0[r2] = -1e30f;
                pmax = fmaxf(pmax, s0[r2]);
            }
            if (c1) {
#pragma unroll
                for (int r2 = 0; r2 < 16; r2++) {
                    int row = (r2 & 3) + 8 * (r2 >> 2) + 4 * H + 32;
                    if (row > dlt) s1[r2] = -1e30f;
                    pmax = fmaxf(pmax, s1[r2]);
                }
            }
            pmax = fmaxf(pmax, __shfl_xor(pmax, 32));
            if (__any(pmax > m + 12.f)) {      // defer-max (log2 units)
                float mn = fmaxf(m, pmax);
                float al = exp2f(m - mn);
                m = mn; lsum *= al;
#pragma unroll
                for (int r2 = 0; r2 < 16; r2++) {
                    float fr = __shfl(al, (r2 & 3) + 8 * (r2 >> 2) + 4 * H);
                    O0[r2] *= fr; O1[r2] *= fr;
                }
            }
            float ps = 0.f;
            u32 pk0[8], pk1[8];
#pragma unroll
            for (int i = 0; i < 8; i++) {
                float a = exp2f(s0[2 * i] - m), bb = exp2f(s0[2 * i + 1] - m);
                ps += a + bb; pk0[i] = cvt_pk_bf16(a, bb);
            }
            if (c1) {
#pragma unroll
                for (int i = 0; i < 8; i++) {
                    float a = exp2f(s1[2 * i] - m), bb = exp2f(s1[2 * i + 1] - m);
                    ps += a + bb; pk1[i] = cvt_pk_bf16(a, bb);
                }
            }
            ps += __shfl_xor(ps, 32);
            lsum += ps;

            // PV: P A-frags via half-exchange (regs 8*(kc&1)+4H..+3 from both halves)
#pragma unroll
            for (int kc = 0; kc < 2; kc++) {
                u32 o0 = H ? pk0[4 * kc + 2] : pk0[4 * kc + 0];
                u32 o1 = H ? pk0[4 * kc + 3] : pk0[4 * kc + 1];
                u32 sd0 = H ? pk0[4 * kc + 0] : pk0[4 * kc + 2];
                u32 sd1 = H ? pk0[4 * kc + 1] : pk0[4 * kc + 3];
                u32 rr0 = (u32)__shfl_xor((int)sd0, 32);
                u32 rr1 = (u32)__shfl_xor((int)sd1, 32);
                u32x4 fv = {H ? rr0 : o0, H ? rr1 : o1, H ? o0 : rr0, H ? o1 : rr1};
                bfrag pA = __builtin_bit_cast(bfrag, fv);
                O0 = mfma32(pA, vB0[kc], O0);
                O1 = mfma32(pA, vB1[kc], O1);
            }
            if (c1) {
#pragma unroll
                for (int kc = 0; kc < 2; kc++) {
                    u32 o0 = H ? pk1[4 * kc + 2] : pk1[4 * kc + 0];
                    u32 o1 = H ? pk1[4 * kc + 3] : pk1[4 * kc + 1];
                    u32 sd0 = H ? pk1[4 * kc + 0] : pk1[4 * kc + 2];
                    u32 sd1 = H ? pk1[4 * kc + 1] : pk1[4 * kc + 3];
                    u32 rr0 = (u32)__shfl_xor((int)sd0, 32);
                    u32 rr1 = (u32)__shfl_xor((int)sd1, 32);
                    u32x4 fv = {H ? rr0 : o0, H ? rr1 : o1, H ? o0 : rr0, H ? o1 : rr1};
                    bfrag pA = __builtin_bit_cast(bfrag, fv);
                    O0 = mfma32(pA, vB0[2 + kc], O0);
                    O1 = mfma32(pA, vB1[2 + kc], O1);
                }
            }
            __syncthreads();
        }
    }

    float linv = 1.f / lsum;
#pragma unroll
    for (int r2 = 0; r2 < 16; r2++) {
        int row = (r2 & 3) + 8 * (r2 >> 2) + 4 * H;
        float fr = __shfl(linv, row);
        size_t base = ((size_t)(b * 2048 + qw0 + row)) * 768 + h * 64;
        o_ws[base + lq] = f2bf(O0[r2] * fr);
        o_ws[base + 32 + lq] = f2bf(O1[r2] * fr);
    }
}

// ---------------- launcher ----------------
extern "C" void kernel_launch(void* const* d_in, const int* in_sizes, int n_in,
                              void* d_out, int out_size, void* d_ws, size_t ws_size,
                              hipStream_t stream) {
    const float* x  = (const float*)d_in[0];
    const float* Wq = (const float*)d_in[1];
    const float* bq = (const float*)d_in[2];
    const float* Wk = (const float*)d_in[3];
    const float* bk = (const float*)d_in[4];
    const float* Wv = (const float*)d_in[5];
    const float* bv = (const float*)d_in[6];
    const float* Wo = (const float*)d_in[7];
    const float* bo = (const float*)d_in[8];
    float* out = (float*)d_out;

    char* p = (char*)d_ws;
    u16* xb  = (u16*)p; p += (size_t)2 * 2048 * 768 * 2;
    u16* wqb = (u16*)p; p += (size_t)768 * 768 * 2;
    u16* wkb = (u16*)p; p += (size_t)768 * 768 * 2;
    u16* wvb = (u16*)p; p += (size_t)768 * 768 * 2;
    u16* wob = (u16*)p; p += (size_t)768 * 768 * 2;
    u16* q_ws = (u16*)p; p += (size_t)24 * 2048 * 64 * 2;   // [bh][s][64], pre-scaled
    u16* k_ws = (u16*)p; p += (size_t)24 * 2048 * 64 * 2;   // [bh][s][64]
    u16* vt_ws = (u16*)p; p += (size_t)24 * 2048 * 64 * 2;  // [bh][d][s] transposed
    u16* o_ws = (u16*)p; p += (size_t)4096 * 768 * 2;       // [b*s][h*d]

    convert_all<<<5376, 256, 0, stream>>>(x, Wq, Wk, Wv, Wo, xb, wqb, wkb, wvb, wob);
    gemm_qkv<<<dim3(32, 18), 256, 0, stream>>>(xb, wqb, wkb, wvb, bq, bk, bv, q_ws, k_ws, vt_ws);
    attn2<<<dim3(384), 256, 0, stream>>>(q_ws, k_ws, vt_ws, o_ws);
    gemm_out<<<dim3(32, 6), 256, 0, stream>>>(o_ws, wob, bo, out);
}